// Round 12
// baseline (179.514 us; speedup 1.0000x reference)
//
#include <hip/hip_runtime.h>

namespace {
constexpr int kV = 256, kO = 128, kE = 1024, kD = 128;
constexpr int kN = kV * kO;    // 32768 nodes
constexpr int kVE = kV * kE;   // 262144 edges
constexpr float kEps = 1e-5f;
}

typedef __attribute__((ext_vector_type(8))) short bf16x8;
typedef __attribute__((ext_vector_type(8))) unsigned short u16x8;
typedef __attribute__((ext_vector_type(4))) float f32x4;

__device__ __forceinline__ unsigned short f2bf(float x) {
  unsigned u = __float_as_uint(x);
  return (unsigned short)((u + 0x7FFFu + ((u >> 16) & 1u)) >> 16);
}
__device__ __forceinline__ float bf2f(unsigned short h) {
  return __uint_as_float((unsigned)h << 16);
}

// ---- K1: per-graph count matrix A[s][o] (bf16 hi/lo, exact) + degrees.
__global__ __launch_bounds__(256) void k_adj(
    const unsigned int* __restrict__ ew,
    int* __restrict__ cnt_s, int* __restrict__ cnt_o,
    unsigned short* __restrict__ Ah, unsigned short* __restrict__ Al) {
  __shared__ int cnt[kO * kO];  // 64 KiB
  __shared__ int anyodd;
  int v = blockIdx.x, t = threadIdx.x;
  if (t == 0) anyodd = 0;
  for (int i = t; i < kO * kO; i += 256) cnt[i] = 0;
  __syncthreads();
  int base = v * 3072, loc = 0;
  for (int i = t; i < 3072; i += 256) {
    int g = base + i;
    if ((g & 1) && ew[g] != 0u) loc = 1;
  }
  if (loc) atomicOr(&anyodd, 1);
  __syncthreads();
  bool is64 = (anyodd == 0);
  for (int e = t; e < kE; e += 256) {
    long long eb = (long long)(v * kE + e) * 3;
    unsigned s, o;
    if (is64) { s = ew[2 * eb]; o = ew[2 * (eb + 2)]; }
    else      { s = ew[eb];     o = ew[eb + 2]; }
    s &= 127u; o &= 127u;
    atomicAdd(&cnt[s * kO + o], 1);
  }
  __syncthreads();
  for (int i = t; i < kO * kO; i += 256) {
    float c = (float)cnt[i];
    unsigned short h = f2bf(c);
    Ah[(size_t)v * 16384 + i] = h;
    Al[(size_t)v * 16384 + i] = f2bf(c - bf2f(h));
  }
  if (t < kO) {
    int s = 0;
    for (int c = 0; c < kO; ++c) s += cnt[t * kO + ((c + t) & 127)];
    cnt_s[v * kO + t] = s;
  } else {
    int tc = t - kO;
    int s = 0;
    for (int r = 0; r < kO; ++r) s += cnt[((r + tc) & 127) * kO + tc];
    cnt_o[v * kO + tc] = s;
  }
}

// ---- K1b: split weight matrices into bf16 hi/lo ----
__global__ __launch_bounds__(256) void k_wsplit(
    const float* __restrict__ s0, const float* __restrict__ s1,
    const float* __restrict__ s2, const float* __restrict__ s3,
    unsigned short* __restrict__ h0, unsigned short* __restrict__ l0,
    unsigned short* __restrict__ h1, unsigned short* __restrict__ l1,
    unsigned short* __restrict__ h2, unsigned short* __restrict__ l2,
    unsigned short* __restrict__ h3, unsigned short* __restrict__ l3) {
  const float* s[4] = {s0, s1, s2, s3};
  unsigned short* hh[4] = {h0, h1, h2, h3};
  unsigned short* ll[4] = {l0, l1, l2, l3};
  const int ns[4] = {kD * 2 * kD, kD * kD, kD * 2 * kD, kD * kD};
  int i0 = blockIdx.x * 256 + threadIdx.x, stride = gridDim.x * 256;
#pragma unroll
  for (int a = 0; a < 4; ++a) {
    for (int i = i0; i < ns[a]; i += stride) {
      float x = s[a][i];
      unsigned short hb = f2bf(x);
      hh[a][i] = hb;
      ll[a][i] = f2bf(x - bf2f(hb));
    }
  }
}

// ---- K2: count-weighted per-column sums/sumsq (BN1 partials), 64 rows/block ----
__global__ __launch_bounds__(256) void k_stats1(
    const float* __restrict__ x, const int* __restrict__ cnt_s,
    const int* __restrict__ cnt_o, float* __restrict__ p1) {
  __shared__ float red[8][128];
  int b = blockIdx.x, t = threadIdx.x;
  int dq = (t & 31) * 4, rg = t >> 5;
  float acc[4][4];
#pragma unroll
  for (int a = 0; a < 4; ++a)
#pragma unroll
    for (int j = 0; j < 4; ++j) acc[a][j] = 0.f;
  for (int k = 0; k < 8; ++k) {
    int n = b * 64 + rg + k * 8;
    float4 xv = *(const float4*)(x + (size_t)n * kD + dq);
    float wsv = (float)cnt_s[n], wov = (float)cnt_o[n];
    float xs[4] = {xv.x, xv.y, xv.z, xv.w};
#pragma unroll
    for (int j = 0; j < 4; ++j) {
      acc[0][j] += wsv * xs[j];
      acc[1][j] += wsv * xs[j] * xs[j];
      acc[2][j] += wov * xs[j];
      acc[3][j] += wov * xs[j] * xs[j];
    }
  }
  for (int st = 0; st < 4; ++st) {
    __syncthreads();
#pragma unroll
    for (int j = 0; j < 4; ++j) red[rg][dq + j] = acc[st][j];
    __syncthreads();
    if (t < 128) {
      float s = 0.f;
#pragma unroll
      for (int g = 0; g < 8; ++g) s += red[g][t];
      p1[((size_t)b * 4 + st) * 128 + t] = s;
    }
  }
}

// ---- K3: finalize BN1 coeffs — 256 blocks (one per column), 512 partials ----
__global__ __launch_bounds__(256) void k_fin1(
    const float* __restrict__ p1, const float* __restrict__ g1,
    const float* __restrict__ b1, float* __restrict__ coef) {
  __shared__ double sS[256], sQ[256];
  int c = blockIdx.x, t = threadIdx.x;
  int half = c >> 7, d = c & 127;
  double S = 0.0, Q = 0.0;
#pragma unroll
  for (int r = 0; r < 2; ++r) {
    int b = t + r * 256;
    S += (double)p1[((size_t)b * 4 + half * 2 + 0) * 128 + d];
    Q += (double)p1[((size_t)b * 4 + half * 2 + 1) * 128 + d];
  }
  sS[t] = S; sQ[t] = Q;
  __syncthreads();
  for (int s = 128; s > 0; s >>= 1) {
    if (t < s) { sS[t] += sS[t + s]; sQ[t] += sQ[t + s]; }
    __syncthreads();
  }
  if (t == 0) {
    double m = sS[0] / (double)kVE;
    double var = sQ[0] / (double)kVE - m * m;
    float a = g1[c] / sqrtf((float)var + kEps);
    float beta = b1[c] - (float)m * a;
    coef[half * 256 + d] = a;
    coef[half * 256 + 128 + d] = beta;
  }
}

// ---- K4: FUSED per-graph kernel, 512 threads, 64 KiB LDS -> 2 blocks/CU.
// Sequential staging: hs -> ys GEMM, ho -> yo GEMM, yoT transpose, pool, epi.
__global__ __launch_bounds__(512, 4) void k_fused1(
    const float* __restrict__ X,
    const unsigned short* __restrict__ Whi, const unsigned short* __restrict__ Wlo,
    const float* __restrict__ coef,
    const unsigned short* __restrict__ Ah, const unsigned short* __restrict__ Al,
    const int* __restrict__ cnt_s, const float* __restrict__ lb1,
    float* __restrict__ pooled, float* __restrict__ p2) {
  __shared__ __align__(16) unsigned short BH[16384], BL[16384];  // 64 KiB total
  int t = threadIdx.x, v = blockIdx.x;
  int dq = (t & 31) * 4, rg = t >> 5;  // rg 0..15
  int lane = t & 63, wid = t >> 6;     // 8 waves
  int wr = wid * 16, lrow = lane & 15, lkc = lane >> 4;

  // ---- Phase A1: stage hs bf16-split ----
  float4 aS = *(const float4*)(coef + dq), bS = *(const float4*)(coef + 128 + dq);
  for (int k = 0; k < 8; ++k) {
    int r = rg + k * 16;
    float4 xv = *(const float4*)(X + ((size_t)v * kO + r) * kD + dq);
    float h0 = fmaxf(aS.x * xv.x + bS.x, 0.f), h1 = fmaxf(aS.y * xv.y + bS.y, 0.f);
    float h2 = fmaxf(aS.z * xv.z + bS.z, 0.f), h3 = fmaxf(aS.w * xv.w + bS.w, 0.f);
    ushort4 hh, hl;
    hh.x = f2bf(h0); hl.x = f2bf(h0 - bf2f(hh.x));
    hh.y = f2bf(h1); hl.y = f2bf(h1 - bf2f(hh.y));
    hh.z = f2bf(h2); hl.z = f2bf(h2 - bf2f(hh.z));
    hh.w = f2bf(h3); hl.w = f2bf(h3 - bf2f(hh.w));
    int idx = r * 128 + (dq ^ ((r & 7) << 3));
    *(ushort4*)(BH + idx) = hh; *(ushort4*)(BL + idx) = hl;
  }
  __syncthreads();
  // ---- Phase B1: ys GEMM -> accS[8] ----
  f32x4 accS[8];
#pragma unroll
  for (int j = 0; j < 8; ++j) accS[j] = (f32x4){0.f, 0.f, 0.f, 0.f};
  for (int ks = 0; ks < 4; ++ks) {
    int kb = ks * 32 + lkc * 8;
    int ar = wr + lrow;
    int ai = ar * 128 + (kb ^ ((ar & 7) << 3));
    bf16x8 ash = *(const bf16x8*)(BH + ai), asl = *(const bf16x8*)(BL + ai);
#pragma unroll
    for (int jp = 0; jp < 2; ++jp) {
      bf16x8 bh[4], bl[4];
#pragma unroll
      for (int p = 0; p < 4; ++p) {
        int j = (jp * 4 + p) * 16 + lrow;
        size_t wo = (size_t)j * 256 + kb;
        bh[p] = *(const bf16x8*)(Whi + wo);
        bl[p] = *(const bf16x8*)(Wlo + wo);
      }
#pragma unroll
      for (int p = 0; p < 4; ++p) {
        int jg = jp * 4 + p;
        accS[jg] = __builtin_amdgcn_mfma_f32_16x16x32_bf16(ash, bh[p], accS[jg], 0, 0, 0);
        accS[jg] = __builtin_amdgcn_mfma_f32_16x16x32_bf16(ash, bl[p], accS[jg], 0, 0, 0);
        accS[jg] = __builtin_amdgcn_mfma_f32_16x16x32_bf16(asl, bh[p], accS[jg], 0, 0, 0);
      }
    }
  }
  __syncthreads();
  // ---- Phase A2: stage ho (re-read X, L2-hot) ----
  float4 aO = *(const float4*)(coef + 256 + dq), bO = *(const float4*)(coef + 384 + dq);
  for (int k = 0; k < 8; ++k) {
    int r = rg + k * 16;
    float4 xv = *(const float4*)(X + ((size_t)v * kO + r) * kD + dq);
    float h0 = fmaxf(aO.x * xv.x + bO.x, 0.f), h1 = fmaxf(aO.y * xv.y + bO.y, 0.f);
    float h2 = fmaxf(aO.z * xv.z + bO.z, 0.f), h3 = fmaxf(aO.w * xv.w + bO.w, 0.f);
    ushort4 hh, hl;
    hh.x = f2bf(h0); hl.x = f2bf(h0 - bf2f(hh.x));
    hh.y = f2bf(h1); hl.y = f2bf(h1 - bf2f(hh.y));
    hh.z = f2bf(h2); hl.z = f2bf(h2 - bf2f(hh.z));
    hh.w = f2bf(h3); hl.w = f2bf(h3 - bf2f(hh.w));
    int idx = r * 128 + (dq ^ ((r & 7) << 3));
    *(ushort4*)(BH + idx) = hh; *(ushort4*)(BL + idx) = hl;
  }
  __syncthreads();
  // ---- Phase B2: yo GEMM -> accO[8] ----
  f32x4 accO[8];
#pragma unroll
  for (int j = 0; j < 8; ++j) accO[j] = (f32x4){0.f, 0.f, 0.f, 0.f};
  for (int ks = 0; ks < 4; ++ks) {
    int kb = ks * 32 + lkc * 8;
    int ar = wr + lrow;
    int ai = ar * 128 + (kb ^ ((ar & 7) << 3));
    bf16x8 aoh = *(const bf16x8*)(BH + ai), aol = *(const bf16x8*)(BL + ai);
#pragma unroll
    for (int jp = 0; jp < 2; ++jp) {
      bf16x8 bh[4], bl[4];
#pragma unroll
      for (int p = 0; p < 4; ++p) {
        int j = (jp * 4 + p) * 16 + lrow;
        size_t wo = (size_t)j * 256 + 128 + kb;  // W1b half
        bh[p] = *(const bf16x8*)(Whi + wo);
        bl[p] = *(const bf16x8*)(Wlo + wo);
      }
#pragma unroll
      for (int p = 0; p < 4; ++p) {
        int jg = jp * 4 + p;
        accO[jg] = __builtin_amdgcn_mfma_f32_16x16x32_bf16(aoh, bh[p], accO[jg], 0, 0, 0);
        accO[jg] = __builtin_amdgcn_mfma_f32_16x16x32_bf16(aoh, bl[p], accO[jg], 0, 0, 0);
        accO[jg] = __builtin_amdgcn_mfma_f32_16x16x32_bf16(aol, bh[p], accO[jg], 0, 0, 0);
      }
    }
  }
  __syncthreads();
  // ---- Phase C: transpose accO -> yoT[d][o] in BH/BL (swizzle <<3) ----
#pragma unroll
  for (int jg = 0; jg < 8; ++jg) {
    int d = jg * 16 + lrow;
#pragma unroll
    for (int q = 0; q < 4; ++q) {
      int o = wr + lkc * 4 + q;
      int addr = d * 128 + (o ^ ((d & 7) << 3));
      float vv = accO[jg][q];
      unsigned short h = f2bf(vv);
      BH[addr] = h;
      BL[addr] = f2bf(vv - bf2f(h));
    }
  }
  __syncthreads();
  // ---- Phase D: pool GEMM: A (global, batch-prefetched) x yoT (LDS) ----
  bf16x8 pah[4], pal[4];
#pragma unroll
  for (int ks = 0; ks < 4; ++ks) {
    size_t ao = (size_t)v * 16384 + (size_t)(wr + lrow) * 128 + ks * 32 + lkc * 8;
    pah[ks] = *(const bf16x8*)(Ah + ao);
    pal[ks] = *(const bf16x8*)(Al + ao);
  }
  f32x4 accP[8];
#pragma unroll
  for (int j = 0; j < 8; ++j) accP[j] = (f32x4){0.f, 0.f, 0.f, 0.f};
#pragma unroll
  for (int ks = 0; ks < 4; ++ks) {
    int kb = ks * 32 + lkc * 8;
#pragma unroll
    for (int jg = 0; jg < 8; ++jg) {
      int d = jg * 16 + lrow;
      int qi = d * 128 + (kb ^ ((d & 7) << 3));
      bf16x8 qh = *(const bf16x8*)(BH + qi), ql = *(const bf16x8*)(BL + qi);
      accP[jg] = __builtin_amdgcn_mfma_f32_16x16x32_bf16(pah[ks], qh, accP[jg], 0, 0, 0);
      accP[jg] = __builtin_amdgcn_mfma_f32_16x16x32_bf16(pah[ks], ql, accP[jg], 0, 0, 0);
      accP[jg] = __builtin_amdgcn_mfma_f32_16x16x32_bf16(pal[ks], qh, accP[jg], 0, 0, 0);
    }
  }
  // ---- Phase E: pooled + BN2 partials ----
  float lb[8];
#pragma unroll
  for (int jg = 0; jg < 8; ++jg) lb[jg] = lb1[jg * 16 + lrow];
  float sm[8], sq[8];
#pragma unroll
  for (int jg = 0; jg < 8; ++jg) { sm[jg] = 0.f; sq[jg] = 0.f; }
#pragma unroll
  for (int q = 0; q < 4; ++q) {
    int row = wr + lkc * 4 + q;
    size_t n = (size_t)v * kO + row;
    int cnt = cnt_s[n];
    float inv = (cnt > 0) ? 1.f / (float)cnt : 0.f;
#pragma unroll
    for (int jg = 0; jg < 8; ++jg) {
      int col = jg * 16 + lrow;
      float pv = 0.f;
      if (cnt > 0) pv = accS[jg][q] + lb[jg] + accP[jg][q] * inv;
      pooled[n * kD + col] = pv;
      sm[jg] += pv; sq[jg] += pv * pv;
    }
  }
  __syncthreads();  // all waves done reading yoT; reuse BH as red [32][128]
  float* red = (float*)BH;
  int slot = wid * 4 + lkc;  // 0..31
#pragma unroll
  for (int jg = 0; jg < 8; ++jg) red[slot * 128 + jg * 16 + lrow] = sm[jg];
  __syncthreads();
  if (t < 128) {
    float s = 0.f;
#pragma unroll
    for (int g = 0; g < 32; ++g) s += red[g * 128 + t];
    p2[((size_t)v * 2 + 0) * 128 + t] = s;
  }
  __syncthreads();
#pragma unroll
  for (int jg = 0; jg < 8; ++jg) red[slot * 128 + jg * 16 + lrow] = sq[jg];
  __syncthreads();
  if (t < 128) {
    float s = 0.f;
#pragma unroll
    for (int g = 0; g < 32; ++g) s += red[g * 128 + t];
    p2[((size_t)v * 2 + 1) * 128 + t] = s;
  }
}

// ---- K6: finalize BN2 coeffs — 128 blocks (one per column), 256 partials ----
__global__ __launch_bounds__(256) void k_fin2(
    const float* __restrict__ p2, const float* __restrict__ g2,
    const float* __restrict__ b2, float* __restrict__ coef2) {
  __shared__ double sS[256], sQ[256];
  int d = blockIdx.x, t = threadIdx.x;
  double S = (double)p2[((size_t)t * 2 + 0) * 128 + d];
  double Q = (double)p2[((size_t)t * 2 + 1) * 128 + d];
  sS[t] = S; sQ[t] = Q;
  __syncthreads();
  for (int s = 128; s > 0; s >>= 1) {
    if (t < s) { sS[t] += sS[t + s]; sQ[t] += sQ[t + s]; }
    __syncthreads();
  }
  if (t == 0) {
    double m = sS[0] / (double)kN, var = sQ[0] / (double)kN - m * m;
    float a = g2[d] / sqrtf((float)var + kEps);
    float beta = b2[d] - (float)m * a;
    coef2[d] = a; coef2[128 + d] = beta;
  }
}

// ---- K7: W2 GEMM, 64-row x 128-col tiles, 512 blocks (R11, unchanged) ----
template <int STATS>
__global__ __launch_bounds__(256, 2) void k_gemm(
    const float* __restrict__ X,
    const unsigned short* __restrict__ Whi, const unsigned short* __restrict__ Wlo,
    const float* __restrict__ coefA, const float* __restrict__ coefB,
    float* __restrict__ Y, const float* __restrict__ bias, const float* __restrict__ resid,
    const int* __restrict__ cnt_s, const int* __restrict__ cnt_o,
    float* __restrict__ p1out) {
  __shared__ __align__(16) unsigned short AhL[8192], AlL[8192];
  int t = threadIdx.x, rb = blockIdx.x;
  int dq = (t & 31) * 4, rg = t >> 5;
  float4 av = *(const float4*)(coefA + dq);
  float4 bv = *(const float4*)(coefB + dq);
  for (int k = 0; k < 8; ++k) {
    int r = rg + k * 8;
    float4 xv = *(const float4*)(X + ((size_t)rb * 64 + r) * kD + dq);
    float h[4] = {fmaxf(av.x * xv.x + bv.x, 0.f), fmaxf(av.y * xv.y + bv.y, 0.f),
                  fmaxf(av.z * xv.z + bv.z, 0.f), fmaxf(av.w * xv.w + bv.w, 0.f)};
    ushort4 hi, lo;
    hi.x = f2bf(h[0]); lo.x = f2bf(h[0] - bf2f(hi.x));
    hi.y = f2bf(h[1]); lo.y = f2bf(h[1] - bf2f(hi.y));
    hi.z = f2bf(h[2]); lo.z = f2bf(h[2] - bf2f(hi.z));
    hi.w = f2bf(h[3]); lo.w = f2bf(h[3] - bf2f(hi.w));
    int idx = r * 128 + (dq ^ ((r & 7) << 3));
    *(ushort4*)(AhL + idx) = hi;
    *(ushort4*)(AlL + idx) = lo;
  }
  __syncthreads();
  int lane = t & 63, wid = t >> 6;
  int rh = wid & 1, ch = wid >> 1;
  int wr = rh * 32, lrow = lane & 15, lkc = lane >> 4;
  f32x4 acc[2][4];
#pragma unroll
  for (int i = 0; i < 2; ++i)
#pragma unroll
    for (int j = 0; j < 4; ++j) acc[i][j] = (f32x4){0.f, 0.f, 0.f, 0.f};
  for (int ks = 0; ks < 4; ++ks) {
    int kb = ks * 32 + lkc * 8;
    bf16x8 ah[2], al[2];
#pragma unroll
    for (int ri = 0; ri < 2; ++ri) {
      int ar = wr + ri * 16 + lrow;
      int ai = ar * 128 + (kb ^ ((ar & 7) << 3));
      ah[ri] = *(const bf16x8*)(AhL + ai);
      al[ri] = *(const bf16x8*)(AlL + ai);
    }
    bf16x8 bh[4], bl[4];
#pragma unroll
    for (int jg = 0; jg < 4; ++jg) {
      size_t wo = (size_t)(ch * 64 + jg * 16 + lrow) * 128 + kb;
      bh[jg] = *(const bf16x8*)(Whi + wo);
      bl[jg] = *(const bf16x8*)(Wlo + wo);
    }
#pragma unroll
    for (int jg = 0; jg < 4; ++jg)
#pragma unroll
      for (int ri = 0; ri < 2; ++ri) {
        acc[ri][jg] = __builtin_amdgcn_mfma_f32_16x16x32_bf16(ah[ri], bh[jg], acc[ri][jg], 0, 0, 0);
        acc[ri][jg] = __builtin_amdgcn_mfma_f32_16x16x32_bf16(ah[ri], bl[jg], acc[ri][jg], 0, 0, 0);
        acc[ri][jg] = __builtin_amdgcn_mfma_f32_16x16x32_bf16(al[ri], bh[jg], acc[ri][jg], 0, 0, 0);
      }
  }
  float s0[4], s1[4], s2[4], s3[4];
  if (STATS) {
#pragma unroll
    for (int jg = 0; jg < 4; ++jg) { s0[jg] = 0.f; s1[jg] = 0.f; s2[jg] = 0.f; s3[jg] = 0.f; }
  }
#pragma unroll
  for (int ri = 0; ri < 2; ++ri) {
    float wsr[4], wor[4];
    if (STATS) {
#pragma unroll
      for (int q = 0; q < 4; ++q) {
        int n = rb * 64 + wr + ri * 16 + lkc * 4 + q;
        wsr[q] = (float)cnt_s[n]; wor[q] = (float)cnt_o[n];
      }
    }
#pragma unroll
    for (int jg = 0; jg < 4; ++jg) {
      int col = ch * 64 + jg * 16 + lrow;
      float bcol = bias ? bias[col] : 0.f;
#pragma unroll
      for (int q = 0; q < 4; ++q) {
        int row = wr + ri * 16 + lkc * 4 + q;
        size_t n = (size_t)rb * 64 + row;
        float vv = acc[ri][jg][q] + bcol;
        if (resid) vv += resid[n * kD + col];
        Y[n * kD + col] = vv;
        if (STATS) {
          s0[jg] += wsr[q] * vv; s1[jg] += wsr[q] * vv * vv;
          s2[jg] += wor[q] * vv; s3[jg] += wor[q] * vv * vv;
        }
      }
    }
  }
  if (STATS) {
    __syncthreads();
    float* red = (float*)AhL;  // [4 stats][8][128] = 16 KiB
    int slot = rh * 4 + lkc;
#pragma unroll
    for (int jg = 0; jg < 4; ++jg) {
      int col = ch * 64 + jg * 16 + lrow;
      red[0 * 1024 + slot * 128 + col] = s0[jg];
      red[1 * 1024 + slot * 128 + col] = s1[jg];
      red[2 * 1024 + slot * 128 + col] = s2[jg];
      red[3 * 1024 + slot * 128 + col] = s3[jg];
    }
    __syncthreads();
    if (t < 128) {
#pragma unroll
      for (int st = 0; st < 4; ++st) {
        float s = 0.f;
#pragma unroll
        for (int g = 0; g < 8; ++g) s += red[st * 1024 + g * 128 + t];
        p1out[((size_t)rb * 4 + st) * 128 + t] = s;
      }
    }
  }
}

extern "C" void kernel_launch(void* const* d_in, const int* in_sizes, int n_in,
                              void* d_out, int out_size, void* d_ws, size_t ws_size,
                              hipStream_t stream) {
  (void)in_sizes; (void)n_in; (void)out_size; (void)ws_size;
  const float* obj = (const float*)d_in[0];
  const unsigned int* ew = (const unsigned int*)d_in[1];
  const float* prm[2][8];
  for (int u = 0; u < 2; ++u)
    for (int p = 0; p < 8; ++p) prm[u][p] = (const float*)d_in[2 + u * 8 + p];
  // prm[u]: 0=g1 1=b1 2=W1 3=lb1 4=g2 5=b2 6=W2 7=lb2

  char* ws = (char*)d_ws;
  size_t off = 0;
  auto carve = [&](size_t bytes) -> char* {
    char* p = ws + off;
    off = (off + bytes + 255) & ~(size_t)255;
    return p;
  };
  int* cnt_s = (int*)carve((size_t)kN * 4);
  int* cnt_o = (int*)carve((size_t)kN * 4);
  unsigned short* Abh = (unsigned short*)carve((size_t)kV * 16384 * 2);
  unsigned short* Abl = (unsigned short*)carve((size_t)kV * 16384 * 2);
  float* p1 = (float*)carve((size_t)512 * 4 * 128 * 4);
  float* p2 = (float*)carve((size_t)kV * 2 * 128 * 4);
  float* coef1 = (float*)carve(512 * 4);
  float* coef2 = (float*)carve(256 * 4);
  unsigned short *w1hi[2], *w1lo[2], *w2hi[2], *w2lo[2];
  for (int u = 0; u < 2; ++u) {
    w1hi[u] = (unsigned short*)carve((size_t)kD * 2 * kD * 2);
    w1lo[u] = (unsigned short*)carve((size_t)kD * 2 * kD * 2);
    w2hi[u] = (unsigned short*)carve((size_t)kD * kD * 2);
    w2lo[u] = (unsigned short*)carve((size_t)kD * kD * 2);
  }
  float* pooled = (float*)carve((size_t)kN * kD * 4);
  float* x2 = (float*)carve((size_t)kN * kD * 4);

  k_adj<<<kV, 256, 0, stream>>>(ew, cnt_s, cnt_o, Abh, Abl);
  k_wsplit<<<128, 256, 0, stream>>>(prm[0][2], prm[0][6], prm[1][2], prm[1][6],
                                    w1hi[0], w1lo[0], w2hi[0], w2lo[0],
                                    w1hi[1], w1lo[1], w2hi[1], w2lo[1]);

  float* outp = (float*)d_out;
  // ---- unit 0 ----
  k_stats1<<<512, 256, 0, stream>>>(obj, cnt_s, cnt_o, p1);
  k_fin1<<<256, 256, 0, stream>>>(p1, prm[0][0], prm[0][1], coef1);
  k_fused1<<<kV, 512, 0, stream>>>(obj, w1hi[0], w1lo[0], coef1, Abh, Abl,
                                   cnt_s, prm[0][3], pooled, p2);
  k_fin2<<<128, 256, 0, stream>>>(p2, prm[0][4], prm[0][5], coef2);
  k_gemm<1><<<512, 256, 0, stream>>>(pooled, w2hi[0], w2lo[0], coef2, coef2 + 128,
                                     x2, prm[0][7], nullptr, cnt_s, cnt_o, p1);
  // ---- unit 1 ----
  k_fin1<<<256, 256, 0, stream>>>(p1, prm[1][0], prm[1][1], coef1);
  k_fused1<<<kV, 512, 0, stream>>>(x2, w1hi[1], w1lo[1], coef1, Abh, Abl,
                                   cnt_s, prm[1][3], pooled, p2);
  k_fin2<<<128, 256, 0, stream>>>(p2, prm[1][4], prm[1][5], coef2);
  k_gemm<0><<<512, 256, 0, stream>>>(pooled, w2hi[1], w2lo[1], coef2, coef2 + 128,
                                     outp, prm[1][7], obj, nullptr, nullptr, nullptr);
}

// Round 13
// 158.526 us; speedup vs baseline: 1.1324x; 1.1324x over previous
//
#include <hip/hip_runtime.h>

namespace {
constexpr int kV = 256, kO = 128, kE = 1024, kD = 128;
constexpr int kN = kV * kO;    // 32768 nodes
constexpr int kVE = kV * kE;   // 262144 edges
constexpr float kEps = 1e-5f;
}

typedef __attribute__((ext_vector_type(8))) short bf16x8;
typedef __attribute__((ext_vector_type(8))) unsigned short u16x8;
typedef __attribute__((ext_vector_type(4))) float f32x4;

__device__ __forceinline__ unsigned short f2bf(float x) {
  unsigned u = __float_as_uint(x);
  return (unsigned short)((u + 0x7FFFu + ((u >> 16) & 1u)) >> 16);
}
__device__ __forceinline__ float bf2f(unsigned short h) {
  return __uint_as_float((unsigned)h << 16);
}

// ---- K1: per-graph count matrix A[s][o] -> swizzled u16 + degrees +
// fused unit-0 BN1 stats (p1 slot v). Swizzle: elem (row,k) stored at
// row*128 + ((k/8 ^ (row&7))*8) + k%8  (16B-group XOR within row).
__global__ __launch_bounds__(256) void k_adj(
    const unsigned int* __restrict__ ew, const float* __restrict__ X,
    int* __restrict__ cnt_s, int* __restrict__ cnt_o,
    unsigned short* __restrict__ Au16, float* __restrict__ p1) {
  __shared__ int cnt[kO * kO];  // 64 KiB (reused as float red later)
  __shared__ int degS[kO], degO[kO];
  __shared__ int anyodd;
  int v = blockIdx.x, t = threadIdx.x;
  if (t == 0) anyodd = 0;
  for (int i = t; i < kO * kO; i += 256) cnt[i] = 0;
  __syncthreads();
  int base = v * 3072, loc = 0;
  for (int i = t; i < 3072; i += 256) {
    int g = base + i;
    if ((g & 1) && ew[g] != 0u) loc = 1;
  }
  if (loc) atomicOr(&anyodd, 1);
  __syncthreads();
  bool is64 = (anyodd == 0);
  for (int e = t; e < kE; e += 256) {
    long long eb = (long long)(v * kE + e) * 3;
    unsigned s, o;
    if (is64) { s = ew[2 * eb]; o = ew[2 * (eb + 2)]; }
    else      { s = ew[eb];     o = ew[eb + 2]; }
    s &= 127u; o &= 127u;
    atomicAdd(&cnt[s * kO + o], 1);
  }
  __syncthreads();
  // write swizzled u16 A (u32 pairs: k even, k&7<=6 -> same 8-group)
  unsigned int* A32 = (unsigned int*)(Au16 + (size_t)v * 16384);
  for (int i2 = t; i2 < 8192; i2 += 256) {
    int i = 2 * i2;
    int row = i >> 7, k = i & 127, kg = k >> 3;
    int j = row * 128 + ((kg ^ (row & 7)) << 3) + (k & 7);
    unsigned lo = (unsigned)cnt[i], hi = (unsigned)cnt[i + 1];
    A32[j >> 1] = lo | (hi << 16);
  }
  // degrees
  if (t < kO) {
    int s = 0;
    for (int c = 0; c < kO; ++c) s += cnt[t * kO + ((c + t) & 127)];
    degS[t] = s;
    cnt_s[v * kO + t] = s;
  } else {
    int tc = t - kO;
    int s = 0;
    for (int r = 0; r < kO; ++r) s += cnt[((r + tc) & 127) * kO + tc];
    degO[tc] = s;
    cnt_o[v * kO + tc] = s;
  }
  __syncthreads();
  // fused unit-0 BN1 stats over this graph's 128 rows
  int dq = (t & 31) * 4, rg = t >> 5;
  float acc[4][4];
#pragma unroll
  for (int a = 0; a < 4; ++a)
#pragma unroll
    for (int j = 0; j < 4; ++j) acc[a][j] = 0.f;
  for (int k = 0; k < 16; ++k) {
    int row = rg + k * 8;
    float4 xv = *(const float4*)(X + ((size_t)v * kO + row) * kD + dq);
    float wsv = (float)degS[row], wov = (float)degO[row];
    float xs[4] = {xv.x, xv.y, xv.z, xv.w};
#pragma unroll
    for (int j = 0; j < 4; ++j) {
      acc[0][j] += wsv * xs[j];
      acc[1][j] += wsv * xs[j] * xs[j];
      acc[2][j] += wov * xs[j];
      acc[3][j] += wov * xs[j] * xs[j];
    }
  }
  float* red = (float*)cnt;  // reuse
  for (int st = 0; st < 4; ++st) {
    __syncthreads();
#pragma unroll
    for (int j = 0; j < 4; ++j) red[rg * 128 + dq + j] = acc[st][j];
    __syncthreads();
    if (t < 128) {
      float s = 0.f;
#pragma unroll
      for (int g = 0; g < 8; ++g) s += red[g * 128 + t];
      p1[((size_t)v * 4 + st) * 128 + t] = s;
    }
  }
}

// ---- K1b: split weight matrices into bf16 hi/lo ----
__global__ __launch_bounds__(256) void k_wsplit(
    const float* __restrict__ s0, const float* __restrict__ s1,
    const float* __restrict__ s2, const float* __restrict__ s3,
    unsigned short* __restrict__ h0, unsigned short* __restrict__ l0,
    unsigned short* __restrict__ h1, unsigned short* __restrict__ l1,
    unsigned short* __restrict__ h2, unsigned short* __restrict__ l2,
    unsigned short* __restrict__ h3, unsigned short* __restrict__ l3) {
  const float* s[4] = {s0, s1, s2, s3};
  unsigned short* hh[4] = {h0, h1, h2, h3};
  unsigned short* ll[4] = {l0, l1, l2, l3};
  const int ns[4] = {kD * 2 * kD, kD * kD, kD * 2 * kD, kD * kD};
  int i0 = blockIdx.x * 256 + threadIdx.x, stride = gridDim.x * 256;
#pragma unroll
  for (int a = 0; a < 4; ++a) {
    for (int i = i0; i < ns[a]; i += stride) {
      float x = s[a][i];
      unsigned short hb = f2bf(x);
      hh[a][i] = hb;
      ll[a][i] = f2bf(x - bf2f(hb));
    }
  }
}

// ---- K3: finalize BN1 coeffs — 256 blocks (one per column), nslots partials
__global__ __launch_bounds__(256) void k_fin1(
    const float* __restrict__ p1, const float* __restrict__ g1,
    const float* __restrict__ b1, float* __restrict__ coef, int nslots) {
  __shared__ double sS[256], sQ[256];
  int c = blockIdx.x, t = threadIdx.x;
  int half = c >> 7, d = c & 127;
  double S = 0.0, Q = 0.0;
  for (int b = t; b < nslots; b += 256) {
    S += (double)p1[((size_t)b * 4 + half * 2 + 0) * 128 + d];
    Q += (double)p1[((size_t)b * 4 + half * 2 + 1) * 128 + d];
  }
  sS[t] = S; sQ[t] = Q;
  __syncthreads();
  for (int s = 128; s > 0; s >>= 1) {
    if (t < s) { sS[t] += sS[t + s]; sQ[t] += sQ[t + s]; }
    __syncthreads();
  }
  if (t == 0) {
    double m = sS[0] / (double)kVE;
    double var = sQ[0] / (double)kVE - m * m;
    float a = g1[c] / sqrtf((float)var + kEps);
    float beta = b1[c] - (float)m * a;
    coef[half * 256 + d] = a;
    coef[half * 256 + 128 + d] = beta;
  }
}

// ---- K4: FUSED per-graph kernel, 1024 threads (16 waves, 4/SIMD).
// A(u16, pre-swizzled) prefetched into REGISTERS at entry (latency hidden
// under phases A-C), spilled to ToH LDS in phase C, consumed from LDS in D.
__global__ __launch_bounds__(1024, 1) void k_fused1(
    const float* __restrict__ X,
    const unsigned short* __restrict__ Whi, const unsigned short* __restrict__ Wlo,
    const float* __restrict__ coef,
    const unsigned short* __restrict__ Au16,
    const int* __restrict__ cnt_s, const float* __restrict__ lb1,
    float* __restrict__ pooled, float* __restrict__ p2) {
  __shared__ __align__(16) unsigned short TsH[16384], TsL[16384];  // hs, later yoT
  __shared__ __align__(16) unsigned short ToH[16384], ToL[16384];  // ho, later A / red
  int t = threadIdx.x, v = blockIdx.x;
  // ---- entry: prefetch this block's A (32 KB) into regs ----
  u16x8 apre0 = *(const u16x8*)(Au16 + (size_t)v * 16384 + t * 16);
  u16x8 apre1 = *(const u16x8*)(Au16 + (size_t)v * 16384 + t * 16 + 8);
  int dq = (t & 31) * 4, rg = t >> 5;  // rg 0..31
  float4 aS = *(const float4*)(coef + dq),       bS = *(const float4*)(coef + 128 + dq);
  float4 aO = *(const float4*)(coef + 256 + dq), bO = *(const float4*)(coef + 384 + dq);
  for (int k = 0; k < 4; ++k) {
    int r = rg + k * 32;
    float4 xv = *(const float4*)(X + ((size_t)v * kO + r) * kD + dq);
    float hs[4] = {fmaxf(aS.x * xv.x + bS.x, 0.f), fmaxf(aS.y * xv.y + bS.y, 0.f),
                   fmaxf(aS.z * xv.z + bS.z, 0.f), fmaxf(aS.w * xv.w + bS.w, 0.f)};
    float ho[4] = {fmaxf(aO.x * xv.x + bO.x, 0.f), fmaxf(aO.y * xv.y + bO.y, 0.f),
                   fmaxf(aO.z * xv.z + bO.z, 0.f), fmaxf(aO.w * xv.w + bO.w, 0.f)};
    ushort4 sh, sl, oh, ol;
    sh.x = f2bf(hs[0]); sl.x = f2bf(hs[0] - bf2f(sh.x));
    sh.y = f2bf(hs[1]); sl.y = f2bf(hs[1] - bf2f(sh.y));
    sh.z = f2bf(hs[2]); sl.z = f2bf(hs[2] - bf2f(sh.z));
    sh.w = f2bf(hs[3]); sl.w = f2bf(hs[3] - bf2f(sh.w));
    oh.x = f2bf(ho[0]); ol.x = f2bf(ho[0] - bf2f(oh.x));
    oh.y = f2bf(ho[1]); ol.y = f2bf(ho[1] - bf2f(oh.y));
    oh.z = f2bf(ho[2]); ol.z = f2bf(ho[2] - bf2f(oh.z));
    oh.w = f2bf(ho[3]); ol.w = f2bf(ho[3] - bf2f(oh.w));
    int idx = r * 128 + (dq ^ ((r & 7) << 3));
    *(ushort4*)(TsH + idx) = sh; *(ushort4*)(TsL + idx) = sl;
    *(ushort4*)(ToH + idx) = oh; *(ushort4*)(ToL + idx) = ol;
  }
  __syncthreads();
  int lane = t & 63, wid = t >> 6;        // 16 waves
  int wr = (wid & 7) * 16, ch = wid >> 3; // 16 rows x 64-col half
  int lrow = lane & 15, lkc = lane >> 4;
  f32x4 accS[4], accO[4];
#pragma unroll
  for (int j = 0; j < 4; ++j) {
    accS[j] = (f32x4){0.f, 0.f, 0.f, 0.f};
    accO[j] = (f32x4){0.f, 0.f, 0.f, 0.f};
  }
  for (int ks = 0; ks < 4; ++ks) {
    int kb = ks * 32 + lkc * 8;
    int ar = wr + lrow;
    int ai = ar * 128 + (kb ^ ((ar & 7) << 3));
    bf16x8 ash = *(const bf16x8*)(TsH + ai), asl = *(const bf16x8*)(TsL + ai);
    bf16x8 aoh = *(const bf16x8*)(ToH + ai), aol = *(const bf16x8*)(ToL + ai);
#pragma unroll
    for (int jp = 0; jp < 2; ++jp) {
      bf16x8 wsh[2], wsl[2], woh[2], wol[2];
#pragma unroll
      for (int p = 0; p < 2; ++p) {
        int j = ch * 64 + (jp * 2 + p) * 16 + lrow;
        size_t wo = (size_t)j * 256 + kb;
        wsh[p] = *(const bf16x8*)(Whi + wo);
        wsl[p] = *(const bf16x8*)(Wlo + wo);
        woh[p] = *(const bf16x8*)(Whi + wo + 128);
        wol[p] = *(const bf16x8*)(Wlo + wo + 128);
      }
#pragma unroll
      for (int p = 0; p < 2; ++p) {
        int jg = jp * 2 + p;
        accS[jg] = __builtin_amdgcn_mfma_f32_16x16x32_bf16(ash, wsh[p], accS[jg], 0, 0, 0);
        accS[jg] = __builtin_amdgcn_mfma_f32_16x16x32_bf16(ash, wsl[p], accS[jg], 0, 0, 0);
        accS[jg] = __builtin_amdgcn_mfma_f32_16x16x32_bf16(asl, wsh[p], accS[jg], 0, 0, 0);
        accO[jg] = __builtin_amdgcn_mfma_f32_16x16x32_bf16(aoh, woh[p], accO[jg], 0, 0, 0);
        accO[jg] = __builtin_amdgcn_mfma_f32_16x16x32_bf16(aoh, wol[p], accO[jg], 0, 0, 0);
        accO[jg] = __builtin_amdgcn_mfma_f32_16x16x32_bf16(aol, woh[p], accO[jg], 0, 0, 0);
      }
    }
  }
  __syncthreads();
  // ---- Phase C: yoT -> TsH/TsL (swizzle <<3); A regs -> ToH (linear copy) ----
#pragma unroll
  for (int jg = 0; jg < 4; ++jg) {
    int d = ch * 64 + jg * 16 + lrow;
#pragma unroll
    for (int q = 0; q < 4; ++q) {
      int o = wr + lkc * 4 + q;
      int addr = d * 128 + (o ^ ((d & 7) << 3));
      float vv = accO[jg][q];
      unsigned short h = f2bf(vv);
      TsH[addr] = h;
      TsL[addr] = f2bf(vv - bf2f(h));
    }
  }
  *(u16x8*)(ToH + t * 16) = apre0;
  *(u16x8*)(ToH + t * 16 + 8) = apre1;
  __syncthreads();
  // ---- Phase D: pool GEMM: A (LDS u16 -> bf16 hi/lo) x yoT (LDS) ----
  f32x4 accP[4];
#pragma unroll
  for (int j = 0; j < 4; ++j) accP[j] = (f32x4){0.f, 0.f, 0.f, 0.f};
#pragma unroll
  for (int ks = 0; ks < 4; ++ks) {
    int kb = ks * 32 + lkc * 8;
    int row = wr + lrow;
    int kg = ks * 4 + lkc;
    u16x8 au = *(const u16x8*)(ToH + row * 128 + ((kg ^ (row & 7)) << 3));
    bf16x8 pah, pal;
#pragma unroll
    for (int e = 0; e < 8; ++e) {
      float c = (float)au[e];
      unsigned short hb = f2bf(c);
      pah[e] = (short)hb;
      pal[e] = (short)f2bf(c - bf2f(hb));
    }
#pragma unroll
    for (int jg = 0; jg < 4; ++jg) {
      int d = ch * 64 + jg * 16 + lrow;
      int qi = d * 128 + (kb ^ ((d & 7) << 3));
      bf16x8 qh = *(const bf16x8*)(TsH + qi), ql = *(const bf16x8*)(TsL + qi);
      accP[jg] = __builtin_amdgcn_mfma_f32_16x16x32_bf16(pah, qh, accP[jg], 0, 0, 0);
      accP[jg] = __builtin_amdgcn_mfma_f32_16x16x32_bf16(pah, ql, accP[jg], 0, 0, 0);
      accP[jg] = __builtin_amdgcn_mfma_f32_16x16x32_bf16(pal, qh, accP[jg], 0, 0, 0);
    }
  }
  // ---- Phase E: pooled + BN2 partials (red scratch in ToL) ----
  float lb[4];
#pragma unroll
  for (int jg = 0; jg < 4; ++jg) lb[jg] = lb1[ch * 64 + jg * 16 + lrow];
  float sm[4], sq[4];
#pragma unroll
  for (int jg = 0; jg < 4; ++jg) { sm[jg] = 0.f; sq[jg] = 0.f; }
#pragma unroll
  for (int q = 0; q < 4; ++q) {
    int row = wr + lkc * 4 + q;
    size_t n = (size_t)v * kO + row;
    int cnt = cnt_s[n];
    float inv = (cnt > 0) ? 1.f / (float)cnt : 0.f;
#pragma unroll
    for (int jg = 0; jg < 4; ++jg) {
      int col = ch * 64 + jg * 16 + lrow;
      float pv = 0.f;
      if (cnt > 0) pv = accS[jg][q] + lb[jg] + accP[jg][q] * inv;
      pooled[n * kD + col] = pv;
      sm[jg] += pv; sq[jg] += pv * pv;
    }
  }
  __syncthreads();  // ToL free after phase B; use as red [64][128] f32
  float* red = (float*)ToL;
  int slot = (wid & 7) * 4 + lkc;  // 0..31 row-slot; ch selects col-half
#pragma unroll
  for (int jg = 0; jg < 4; ++jg)
    red[(slot * 2 + ch) * 128 + ch * 64 + jg * 16 + lrow] = sm[jg];
  __syncthreads();
  if (t < 128) {
    float s = 0.f;
#pragma unroll
    for (int g = 0; g < 32; ++g) s += red[(g * 2 + (t >> 6)) * 128 + t];
    p2[((size_t)v * 2 + 0) * 128 + t] = s;
  }
  __syncthreads();
#pragma unroll
  for (int jg = 0; jg < 4; ++jg)
    red[(slot * 2 + ch) * 128 + ch * 64 + jg * 16 + lrow] = sq[jg];
  __syncthreads();
  if (t < 128) {
    float s = 0.f;
#pragma unroll
    for (int g = 0; g < 32; ++g) s += red[(g * 2 + (t >> 6)) * 128 + t];
    p2[((size_t)v * 2 + 1) * 128 + t] = s;
  }
}

// ---- K6: finalize BN2 coeffs — 128 blocks (one per column), 256 partials ----
__global__ __launch_bounds__(256) void k_fin2(
    const float* __restrict__ p2, const float* __restrict__ g2,
    const float* __restrict__ b2, float* __restrict__ coef2) {
  __shared__ double sS[256], sQ[256];
  int d = blockIdx.x, t = threadIdx.x;
  double S = (double)p2[((size_t)t * 2 + 0) * 128 + d];
  double Q = (double)p2[((size_t)t * 2 + 1) * 128 + d];
  sS[t] = S; sQ[t] = Q;
  __syncthreads();
  for (int s = 128; s > 0; s >>= 1) {
    if (t < s) { sS[t] += sS[t + s]; sQ[t] += sQ[t + s]; }
    __syncthreads();
  }
  if (t == 0) {
    double m = sS[0] / (double)kN, var = sQ[0] / (double)kN - m * m;
    float a = g2[d] / sqrtf((float)var + kEps);
    float beta = b2[d] - (float)m * a;
    coef2[d] = a; coef2[128 + d] = beta;
  }
}

// ---- K7: W2 GEMM, 64-row x 128-col tiles, 512 blocks (R11, unchanged) ----
template <int STATS>
__global__ __launch_bounds__(256, 2) void k_gemm(
    const float* __restrict__ X,
    const unsigned short* __restrict__ Whi, const unsigned short* __restrict__ Wlo,
    const float* __restrict__ coefA, const float* __restrict__ coefB,
    float* __restrict__ Y, const float* __restrict__ bias, const float* __restrict__ resid,
    const int* __restrict__ cnt_s, const int* __restrict__ cnt_o,
    float* __restrict__ p1out) {
  __shared__ __align__(16) unsigned short AhL[8192], AlL[8192];
  int t = threadIdx.x, rb = blockIdx.x;
  int dq = (t & 31) * 4, rg = t >> 5;
  float4 av = *(const float4*)(coefA + dq);
  float4 bv = *(const float4*)(coefB + dq);
  for (int k = 0; k < 8; ++k) {
    int r = rg + k * 8;
    float4 xv = *(const float4*)(X + ((size_t)rb * 64 + r) * kD + dq);
    float h[4] = {fmaxf(av.x * xv.x + bv.x, 0.f), fmaxf(av.y * xv.y + bv.y, 0.f),
                  fmaxf(av.z * xv.z + bv.z, 0.f), fmaxf(av.w * xv.w + bv.w, 0.f)};
    ushort4 hi, lo;
    hi.x = f2bf(h[0]); lo.x = f2bf(h[0] - bf2f(hi.x));
    hi.y = f2bf(h[1]); lo.y = f2bf(h[1] - bf2f(hi.y));
    hi.z = f2bf(h[2]); lo.z = f2bf(h[2] - bf2f(hi.z));
    hi.w = f2bf(h[3]); lo.w = f2bf(h[3] - bf2f(hi.w));
    int idx = r * 128 + (dq ^ ((r & 7) << 3));
    *(ushort4*)(AhL + idx) = hi;
    *(ushort4*)(AlL + idx) = lo;
  }
  __syncthreads();
  int lane = t & 63, wid = t >> 6;
  int rh = wid & 1, ch = wid >> 1;
  int wr = rh * 32, lrow = lane & 15, lkc = lane >> 4;
  f32x4 acc[2][4];
#pragma unroll
  for (int i = 0; i < 2; ++i)
#pragma unroll
    for (int j = 0; j < 4; ++j) acc[i][j] = (f32x4){0.f, 0.f, 0.f, 0.f};
  for (int ks = 0; ks < 4; ++ks) {
    int kb = ks * 32 + lkc * 8;
    bf16x8 ah[2], al[2];
#pragma unroll
    for (int ri = 0; ri < 2; ++ri) {
      int ar = wr + ri * 16 + lrow;
      int ai = ar * 128 + (kb ^ ((ar & 7) << 3));
      ah[ri] = *(const bf16x8*)(AhL + ai);
      al[ri] = *(const bf16x8*)(AlL + ai);
    }
    bf16x8 bh[4], bl[4];
#pragma unroll
    for (int jg = 0; jg < 4; ++jg) {
      size_t wo = (size_t)(ch * 64 + jg * 16 + lrow) * 128 + kb;
      bh[jg] = *(const bf16x8*)(Whi + wo);
      bl[jg] = *(const bf16x8*)(Wlo + wo);
    }
#pragma unroll
    for (int jg = 0; jg < 4; ++jg)
#pragma unroll
      for (int ri = 0; ri < 2; ++ri) {
        acc[ri][jg] = __builtin_amdgcn_mfma_f32_16x16x32_bf16(ah[ri], bh[jg], acc[ri][jg], 0, 0, 0);
        acc[ri][jg] = __builtin_amdgcn_mfma_f32_16x16x32_bf16(ah[ri], bl[jg], acc[ri][jg], 0, 0, 0);
        acc[ri][jg] = __builtin_amdgcn_mfma_f32_16x16x32_bf16(al[ri], bh[jg], acc[ri][jg], 0, 0, 0);
      }
  }
  float s0[4], s1[4], s2[4], s3[4];
  if (STATS) {
#pragma unroll
    for (int jg = 0; jg < 4; ++jg) { s0[jg] = 0.f; s1[jg] = 0.f; s2[jg] = 0.f; s3[jg] = 0.f; }
  }
#pragma unroll
  for (int ri = 0; ri < 2; ++ri) {
    float wsr[4], wor[4];
    if (STATS) {
#pragma unroll
      for (int q = 0; q < 4; ++q) {
        int n = rb * 64 + wr + ri * 16 + lkc * 4 + q;
        wsr[q] = (float)cnt_s[n]; wor[q] = (float)cnt_o[n];
      }
    }
#pragma unroll
    for (int jg = 0; jg < 4; ++jg) {
      int col = ch * 64 + jg * 16 + lrow;
      float bcol = bias ? bias[col] : 0.f;
#pragma unroll
      for (int q = 0; q < 4; ++q) {
        int row = wr + ri * 16 + lkc * 4 + q;
        size_t n = (size_t)rb * 64 + row;
        float vv = acc[ri][jg][q] + bcol;
        if (resid) vv += resid[n * kD + col];
        Y[n * kD + col] = vv;
        if (STATS) {
          s0[jg] += wsr[q] * vv; s1[jg] += wsr[q] * vv * vv;
          s2[jg] += wor[q] * vv; s3[jg] += wor[q] * vv * vv;
        }
      }
    }
  }
  if (STATS) {
    __syncthreads();
    float* red = (float*)AhL;  // [4 stats][8][128] = 16 KiB
    int slot = rh * 4 + lkc;
#pragma unroll
    for (int jg = 0; jg < 4; ++jg) {
      int col = ch * 64 + jg * 16 + lrow;
      red[0 * 1024 + slot * 128 + col] = s0[jg];
      red[1 * 1024 + slot * 128 + col] = s1[jg];
      red[2 * 1024 + slot * 128 + col] = s2[jg];
      red[3 * 1024 + slot * 128 + col] = s3[jg];
    }
    __syncthreads();
    if (t < 128) {
#pragma unroll
      for (int st = 0; st < 4; ++st) {
        float s = 0.f;
#pragma unroll
        for (int g = 0; g < 8; ++g) s += red[st * 1024 + g * 128 + t];
        p1out[((size_t)rb * 4 + st) * 128 + t] = s;
      }
    }
  }
}

extern "C" void kernel_launch(void* const* d_in, const int* in_sizes, int n_in,
                              void* d_out, int out_size, void* d_ws, size_t ws_size,
                              hipStream_t stream) {
  (void)in_sizes; (void)n_in; (void)out_size; (void)ws_size;
  const float* obj = (const float*)d_in[0];
  const unsigned int* ew = (const unsigned int*)d_in[1];
  const float* prm[2][8];
  for (int u = 0; u < 2; ++u)
    for (int p = 0; p < 8; ++p) prm[u][p] = (const float*)d_in[2 + u * 8 + p];
  // prm[u]: 0=g1 1=b1 2=W1 3=lb1 4=g2 5=b2 6=W2 7=lb2

  char* ws = (char*)d_ws;
  size_t off = 0;
  auto carve = [&](size_t bytes) -> char* {
    char* p = ws + off;
    off = (off + bytes + 255) & ~(size_t)255;
    return p;
  };
  int* cnt_s = (int*)carve((size_t)kN * 4);
  int* cnt_o = (int*)carve((size_t)kN * 4);
  unsigned short* Au16 = (unsigned short*)carve((size_t)kV * 16384 * 2);
  float* p1 = (float*)carve((size_t)512 * 4 * 128 * 4);
  float* p2 = (float*)carve((size_t)kV * 2 * 128 * 4);
  float* coef1 = (float*)carve(512 * 4);
  float* coef2 = (float*)carve(256 * 4);
  unsigned short *w1hi[2], *w1lo[2], *w2hi[2], *w2lo[2];
  for (int u = 0; u < 2; ++u) {
    w1hi[u] = (unsigned short*)carve((size_t)kD * 2 * kD * 2);
    w1lo[u] = (unsigned short*)carve((size_t)kD * 2 * kD * 2);
    w2hi[u] = (unsigned short*)carve((size_t)kD * kD * 2);
    w2lo[u] = (unsigned short*)carve((size_t)kD * kD * 2);
  }
  float* pooled = (float*)carve((size_t)kN * kD * 4);
  float* x2 = (float*)carve((size_t)kN * kD * 4);

  k_adj<<<kV, 256, 0, stream>>>(ew, obj, cnt_s, cnt_o, Au16, p1);
  k_wsplit<<<128, 256, 0, stream>>>(prm[0][2], prm[0][6], prm[1][2], prm[1][6],
                                    w1hi[0], w1lo[0], w2hi[0], w2lo[0],
                                    w1hi[1], w1lo[1], w2hi[1], w2lo[1]);

  float* outp = (float*)d_out;
  // ---- unit 0 ----
  k_fin1<<<256, 256, 0, stream>>>(p1, prm[0][0], prm[0][1], coef1, 256);
  k_fused1<<<kV, 1024, 0, stream>>>(obj, w1hi[0], w1lo[0], coef1, Au16,
                                    cnt_s, prm[0][3], pooled, p2);
  k_fin2<<<128, 256, 0, stream>>>(p2, prm[0][4], prm[0][5], coef2);
  k_gemm<1><<<512, 256, 0, stream>>>(pooled, w2hi[0], w2lo[0], coef2, coef2 + 128,
                                     x2, prm[0][7], nullptr, cnt_s, cnt_o, p1);
  // ---- unit 1 ----
  k_fin1<<<256, 256, 0, stream>>>(p1, prm[1][0], prm[1][1], coef1, 512);
  k_fused1<<<kV, 1024, 0, stream>>>(x2, w1hi[1], w1lo[1], coef1, Au16,
                                    cnt_s, prm[1][3], pooled, p2);
  k_fin2<<<128, 256, 0, stream>>>(p2, prm[1][4], prm[1][5], coef2);
  k_gemm<0><<<512, 256, 0, stream>>>(pooled, w2hi[1], w2lo[1], coef2, coef2 + 128,
                                     outp, prm[1][7], obj, nullptr, nullptr, nullptr);
}